// Round 2
// baseline (160.617 us; speedup 1.0000x reference)
//
#include <hip/hip_runtime.h>
#include <stdint.h>

#define HIDDEN 768
#define EMBED  512
#define BATCH  16
#define SEQ    512
#define NWORDS (BATCH*SEQ)      // 8192
#define PAD_FLAT_IDX 2047       // flat index of words[0, 511, 3]
#define NEG_SLOPE 0.1f
#define NPOOLBLK 2048           // 4 words per block, 128 blocks per batch

__device__ __forceinline__ unsigned short f2bf(float f) {
    unsigned int x = __float_as_uint(f);
    unsigned int r = x + 0x7fffu + ((x >> 16) & 1u);
    return (unsigned short)(r >> 16);
}

// ---------------------------------------------------------------------------
// Kernel 1 (combo): blocks 0..2047 -> pool 4 words each (one per wave).
//   Step A: rebuild the block's batch validity mask (512 bits) from words
//           via 2 int4 loads/thread + ballots into LDS (words is L2-hot:
//           512 KB re-read 128x = 64 MB L2 traffic, ~2 us, overlapped).
//   Step B: per wave, prefix-popcount -> dest row (stable compaction), then
//           gather <=4 table rows (12 independent float4/lane), mean-pool,
//           bf16 -> coalesced row-major store to xseq[dest].
// blocks 2048..2431 -> w_ffn [768,512] f32 -> wt [512,768] bf16 N-major.
// TLP: 2048x4 = 8192 pooling waves (8/SIMD) — R3/R4 proved low-TLP pools
// collapse; this keeps R2's occupancy with 3x the per-lane ILP.
// UNCHANGED (clean attribution of the GEMM schedule change).
// ---------------------------------------------------------------------------
__global__ __launch_bounds__(256) void combo_kernel(const int* __restrict__ words,
                                                    const float* __restrict__ w,
                                                    const float* __restrict__ table,
                                                    unsigned short* __restrict__ xseq,
                                                    unsigned short* __restrict__ wt) {
    if (blockIdx.x < NPOOLBLK) {
        __shared__ unsigned long long mask[8];   // validity bits, seg i = words 64i..64i+63
        int b    = blockIdx.x >> 7;              // batch
        int wave = threadIdx.x >> 6;
        int lane = threadIdx.x & 63;

        // ---- Step A: batch validity mask ----
        int p0 = wave * 64 + lane;               // 0..255
        int p1 = p0 + 256;                       // 256..511
        int4 wa = ((const int4*)words)[b * SEQ + p0];
        int4 wb = ((const int4*)words)[b * SEQ + p1];
        unsigned long long mlo = __ballot((wa.x | wa.y | wa.z | wa.w) != 0);
        unsigned long long mhi = __ballot((wb.x | wb.y | wb.z | wb.w) != 0);
        if (lane == 0) { mask[wave] = mlo; mask[4 + wave] = mhi; }
        __syncthreads();

        // ---- Step B: this wave's word ----
        int s = (blockIdx.x & 127) * 4 + wave;   // wave-uniform word index
        int seg = s >> 6;
        int bit = s & 63;
        int vp = 0, tot = 0;
#pragma unroll
        for (int i = 0; i < 8; ++i) {
            unsigned long long m = mask[i];
            int c = __popcll(m);
            if (i < seg) vp += c;
            tot += c;
        }
        unsigned long long mseg = mask[seg];
        vp += __popcll(mseg & ((1ull << bit) - 1ull));
        bool valid = (mseg >> bit) & 1ull;
        int d = valid ? vp : (tot + (s - vp));   // stable; bijective over [0,SEQ)
        int drow = b * SEQ + d;

        int4 w4 = ((const int4*)words)[b * SEQ + s];
        int cnt = (w4.x != 0) + (w4.y != 0) + (w4.z != 0) + (w4.w != 0);

        float sx[3] = {0.f, 0.f, 0.f}, sy[3] = {0.f, 0.f, 0.f};
        float sz[3] = {0.f, 0.f, 0.f}, sw[3] = {0.f, 0.f, 0.f};
        if (cnt == 0) {
            int pid = words[PAD_FLAT_IDX];
            const float4* rp = (const float4*)(table + (size_t)pid * HIDDEN);
#pragma unroll
            for (int c = 0; c < 3; ++c) {
                float4 v = rp[lane + 64 * c];
                sx[c] = v.x; sy[c] = v.y; sz[c] = v.z; sw[c] = v.w;
            }
            cnt = 1;
        } else {
            int id[4] = {w4.x, w4.y, w4.z, w4.w};
#pragma unroll
            for (int j = 0; j < 4; ++j) {
                if (id[j] != 0) {                // wave-uniform branch
                    const float4* rp = (const float4*)(table + (size_t)id[j] * HIDDEN);
#pragma unroll
                    for (int c = 0; c < 3; ++c) {
                        float4 v = rp[lane + 64 * c];
                        sx[c] += v.x; sy[c] += v.y; sz[c] += v.z; sw[c] += v.w;
                    }
                }
            }
        }
        float inv = 1.0f / (float)cnt;
#pragma unroll
        for (int c = 0; c < 3; ++c) {
            ushort4 o;
            o.x = f2bf(sx[c] * inv); o.y = f2bf(sy[c] * inv);
            o.z = f2bf(sz[c] * inv); o.w = f2bf(sw[c] * inv);
            *(ushort4*)&xseq[(size_t)drow * HIDDEN + (lane + 64 * c) * 4] = o;
        }
    } else {
        // ---- transpose+downcast w[k][n] -> wt[n][k] (R2-verbatim) ----
        __shared__ float tile[32][33];
        int bid = blockIdx.x - NPOOLBLK;        // 0..383
        int k0 = (bid % (HIDDEN / 32)) * 32;
        int n0 = (bid / (HIDDEN / 32)) * 32;
        int tc = threadIdx.x & 31;
        int tr = threadIdx.x >> 5;              // 0..7
#pragma unroll
        for (int i = 0; i < 4; ++i) {
            int r = tr + i * 8;
            tile[r][tc] = w[(size_t)(k0 + r) * EMBED + n0 + tc];
        }
        __syncthreads();
#pragma unroll
        for (int i = 0; i < 4; ++i) {
            int r = tr + i * 8;                 // n offset within tile
            wt[(size_t)(n0 + r) * HIDDEN + k0 + tc] = f2bf(tile[tc][r]);
        }
    }
}

// ---------------------------------------------------------------------------
// Kernel 2: GEMM, C = leaky_relu(A @ Bt^T + bias).
// Tile/waves/fragments are R2-verbatim (128x64x32, 4 waves 2x2, width-16
// global_load_lds). R6 changes (unmeasured yet — resubmitted for bench):
//  (a) T3/T4 counted-vmcnt pipeline: 4 LDS buffers (48 KB), iter t stages
//      step t+2, then `s_waitcnt vmcnt(6); s_barrier` (one barrier/step,
//      never vmcnt(0) until the tail). Removes the per-step full drain
//      (~600 cyc exposed latency vs ~110 cyc of ds_read+MFMA per step).
//      RAW: per-wave counted vmcnt before barrier certifies step t staged.
//      WAR: buf written at iter t last read at iter t-2; drained by lgkmcnt
//      before that wave's barrier t-1, which precedes any iter-t stage.
//  (b) XCD-chunked swizzle, n-fastest: swz=(bid&7)*64+(bid>>3) (bijective,
//      512%8==0). Each XCD's 64 co-resident blocks touch 8 A-panels
//      (1.5 MB) + all of B (0.77 MB) -> fits its 4 MB L2; A re-reads
//      (8x = ~100 MB of L3 traffic before) become L2 hits.
// ---------------------------------------------------------------------------
typedef __attribute__((ext_vector_type(8))) short bf16x8;
typedef __attribute__((ext_vector_type(4))) float f32x4;

__device__ __forceinline__ void load_lds16(const void* g, void* l) {
    __builtin_amdgcn_global_load_lds(
        (const __attribute__((address_space(1))) unsigned int*)g,
        (__attribute__((address_space(3))) unsigned int*)l,
        16, 0, 0);
}

#define BM 128
#define BN 64
#define BK 32
#define NSTEP (HIDDEN / BK)   // 24
#define NBUF 4

__global__ __launch_bounds__(256) void gemm_kernel(const unsigned short* __restrict__ A,
                                                   const unsigned short* __restrict__ Bt,
                                                   const float* __restrict__ bias,
                                                   float* __restrict__ out) {
    __shared__ unsigned short sA[NBUF][BM * BK];   // 4 x 8 KB
    __shared__ unsigned short sB[NBUF][BN * BK];   // 4 x 4 KB

    int tid = threadIdx.x;
    int bid = blockIdx.x;                    // 0..511
    int swz = (bid & 7) * 64 + (bid >> 3);   // XCD-chunked, bijective (512%8==0)
    int m0  = (swz >> 3) * BM;               // n-fastest logical order
    int n0  = (swz & 7) * BN;
    int wave = tid >> 6;
    int lane = tid & 63;
    int wr   = wave >> 1;        // 0..1: 64-row slab
    int wc   = wave & 1;         // 0..1: 32-col slab
    int quad = lane >> 4;        // 0..3
    int l16  = lane & 15;

    f32x4 acc[4][2] = {};

    const unsigned short* ga0 = A  + (size_t)(m0 + (tid >> 2)) * HIDDEN + (tid & 3) * 8;
    const unsigned short* ga1 = A  + (size_t)(m0 + 64 + (tid >> 2)) * HIDDEN + (tid & 3) * 8;
    const unsigned short* gb  = Bt + (size_t)(n0 + (tid >> 2)) * HIDDEN + (tid & 3) * 8;

    // prologue: stage steps 0 and 1
    load_lds16(ga0,      &sA[0][tid * 8]);
    load_lds16(ga1,      &sA[0][(256 + tid) * 8]);
    load_lds16(gb,       &sB[0][tid * 8]);
    load_lds16(ga0 + BK, &sA[1][tid * 8]);
    load_lds16(ga1 + BK, &sA[1][(256 + tid) * 8]);
    load_lds16(gb  + BK, &sB[1][tid * 8]);

#pragma unroll
    for (int t = 0; t < NSTEP; ++t) {
        if (t + 2 < NSTEP) {                 // stage step t+2 (compile-time after unroll)
            const int k0  = (t + 2) * BK;
            const int buf = (t + 2) & (NBUF - 1);
            load_lds16(ga0 + k0, &sA[buf][tid * 8]);
            load_lds16(ga1 + k0, &sA[buf][(256 + tid) * 8]);
            load_lds16(gb  + k0, &sB[buf][tid * 8]);
        }
        // counted wait: step t's 3 loads are the oldest; 6 (steps t+1,t+2)
        // may stay in flight across the barrier. Tail: 3, then 0.
        if (t < NSTEP - 2)
            asm volatile("s_waitcnt vmcnt(6)\n\ts_barrier" ::: "memory");
        else if (t == NSTEP - 2)
            asm volatile("s_waitcnt vmcnt(3)\n\ts_barrier" ::: "memory");
        else
            asm volatile("s_waitcnt vmcnt(0)\n\ts_barrier" ::: "memory");

        const int buf = t & (NBUF - 1);
        bf16x8 af[4], bfr[2];
#pragma unroll
        for (int mt = 0; mt < 4; ++mt)
            af[mt] = *(const bf16x8*)&sA[buf][(wr * 64 + mt * 16 + l16) * BK + quad * 8];
#pragma unroll
        for (int nt = 0; nt < 2; ++nt)
            bfr[nt] = *(const bf16x8*)&sB[buf][(wc * 32 + nt * 16 + l16) * BK + quad * 8];

#pragma unroll
        for (int mt = 0; mt < 4; ++mt)
#pragma unroll
            for (int nt = 0; nt < 2; ++nt)
                acc[mt][nt] = __builtin_amdgcn_mfma_f32_16x16x32_bf16(
                    af[mt], bfr[nt], acc[mt][nt], 0, 0, 0);
    }

    // epilogue: D row = quad*4+r, col = l16 (verified layout, rounds 1-5)
#pragma unroll
    for (int nt = 0; nt < 2; ++nt) {
        int col = n0 + wc * 32 + nt * 16 + l16;
        float bv = bias[col];
#pragma unroll
        for (int mt = 0; mt < 4; ++mt) {
            int rbase = m0 + wr * 64 + mt * 16 + quad * 4;
#pragma unroll
            for (int r = 0; r < 4; ++r) {
                float v = acc[mt][nt][r] + bv;
                v = (v > 0.f) ? v : v * NEG_SLOPE;
                out[(size_t)(rbase + r) * EMBED + col] = v;
            }
        }
    }
}

// ---------------------------------------------------------------------------
extern "C" void kernel_launch(void* const* d_in, const int* in_sizes, int n_in,
                              void* d_out, int out_size, void* d_ws, size_t ws_size,
                              hipStream_t stream) {
    (void)in_sizes; (void)n_in; (void)out_size; (void)ws_size;
    const int*   words = (const int*)d_in[0];
    const float* table = (const float*)d_in[1];
    const float* wffn  = (const float*)d_in[2];
    const float* bffn  = (const float*)d_in[3];
    float* out = (float*)d_out;

    char* ws = (char*)d_ws;
    unsigned short* xseq = (unsigned short*)ws;                       // 12582912 B
    unsigned short* wt   = (unsigned short*)(ws + 12582912);          //   786432 B

    combo_kernel<<<NPOOLBLK + (HIDDEN / 32) * (EMBED / 32), 256, 0, stream>>>(
        words, wffn, table, xseq, wt);
    gemm_kernel<<<NWORDS / BM * (EMBED / BN), 256, 0, stream>>>(xseq, wt, bffn, out);
}